// Round 4
// baseline (276.747 us; speedup 1.0000x reference)
//
#include <hip/hip_runtime.h>

#define SCAN_TPB 256
#define SCAN_EPT 8
#define SCAN_TILE (SCAN_TPB * SCAN_EPT)  // 2048

#define LPAD 136  // LDS bf16 row stride: 272 B, 16B-aligned, banks cycle

typedef __attribute__((ext_vector_type(4))) float floatx4;
typedef __attribute__((ext_vector_type(8))) short bf16x8;

__device__ __forceinline__ unsigned short f32_to_bf16(float f) {
  unsigned u = __float_as_uint(f);
  u = (u + 0x7fffu + ((u >> 16) & 1u)) >> 16;  // RNE
  return (unsigned short)u;
}
__device__ __forceinline__ float bf16lo(unsigned u) {
  return __uint_as_float(u << 16);
}
__device__ __forceinline__ float bf16hi(unsigned u) {
  return __uint_as_float(u & 0xffff0000u);
}
__device__ __forceinline__ unsigned pack2(float a, float b) {
  return (unsigned)f32_to_bf16(a) | ((unsigned)f32_to_bf16(b) << 16);
}

// ---------------------------------------------------------------------------
// Prep: degree count (fire-and-forget int atomics) + feat -> bf16 conversion
// fused in one dispatch. tid<E counts; tid<N*8 converts an 8-float chunk.
// ---------------------------------------------------------------------------
__global__ __launch_bounds__(256) void k_prep(
    const float* __restrict__ feat, const int* __restrict__ dst,
    int* __restrict__ cnt, unsigned short* __restrict__ featb,
    int E, int nChunks) {
  int tid = blockIdx.x * blockDim.x + threadIdx.x;
  if (tid < E) atomicAdd(&cnt[dst[tid]], 1);
  if (tid < nChunks) {
    const float4* fp = reinterpret_cast<const float4*>(feat) + (size_t)tid * 2;
    float4 a = fp[0], b = fp[1];
    uint4 o;
    o.x = pack2(a.x, a.y);
    o.y = pack2(a.z, a.w);
    o.z = pack2(b.x, b.y);
    o.w = pack2(b.z, b.w);
    reinterpret_cast<uint4*>(featb)[tid] = o;
  }
}

// ---------------------------------------------------------------------------
// Hierarchical exclusive scan of cnt[N] -> row_ptr[N] (3 kernels)
// ---------------------------------------------------------------------------
__global__ __launch_bounds__(SCAN_TPB) void k_scan1(
    const int* __restrict__ cnt, int* __restrict__ excl,
    int* __restrict__ partials, int N) {
  __shared__ int s[SCAN_TPB];
  int b = blockIdx.x, t = threadIdx.x;
  int base = b * SCAN_TILE + t * SCAN_EPT;
  int v[SCAN_EPT];
  int sum = 0;
#pragma unroll
  for (int i = 0; i < SCAN_EPT; ++i) {
    int idx = base + i;
    v[i] = (idx < N) ? cnt[idx] : 0;
    sum += v[i];
  }
  s[t] = sum;
  __syncthreads();
  for (int off = 1; off < SCAN_TPB; off <<= 1) {
    int x = (t >= off) ? s[t - off] : 0;
    __syncthreads();
    s[t] += x;
    __syncthreads();
  }
  if (t == SCAN_TPB - 1) partials[b] = s[t];
  int run = (t == 0) ? 0 : s[t - 1];
#pragma unroll
  for (int i = 0; i < SCAN_EPT; ++i) {
    int idx = base + i;
    if (idx < N) excl[idx] = run;
    run += v[i];
  }
}

__global__ __launch_bounds__(256) void k_scan2(int* __restrict__ partials, int P) {
  __shared__ int s[256];
  int t = threadIdx.x;
  s[t] = (t < P) ? partials[t] : 0;
  __syncthreads();
  for (int off = 1; off < 256; off <<= 1) {
    int x = (t >= off) ? s[t - off] : 0;
    __syncthreads();
    s[t] += x;
    __syncthreads();
  }
  if (t < P) partials[t] = (t == 0) ? 0 : s[t - 1];
}

__global__ __launch_bounds__(256) void k_scan3(
    int* __restrict__ excl, const int* __restrict__ partials,
    int* __restrict__ cursor, int N) {
  int n = blockIdx.x * blockDim.x + threadIdx.x;
  if (n < N) {
    int v = excl[n] + partials[n / SCAN_TILE];
    excl[n] = v;
    cursor[n] = v;
  }
}

// ---------------------------------------------------------------------------
// Fill: scatter (src, w) into the node's contiguous CSR bucket
// ---------------------------------------------------------------------------
__global__ __launch_bounds__(256) void k_fill(
    const int* __restrict__ src, const int* __restrict__ dst,
    const float* __restrict__ ew, const float* __restrict__ em,
    int* __restrict__ cursor, int2* __restrict__ csr, int E) {
  int e = blockIdx.x * blockDim.x + threadIdx.x;
  if (e >= E) return;
  int d = dst[e];
  int p = atomicAdd(&cursor[d], 1);
  csr[p] = make_int2(src[e], __float_as_int(ew[e] * em[e]));
}

// ---------------------------------------------------------------------------
// Fused: per-64-node block.
//   LDS: An[64 nodes][128 k] bf16 (k<64 feat row, k>=64 h_neigh),
//        Bw[64 j][128 k]  bf16 (k<64 Ws row j, k>=64 Wn row j).  34.8 KB
//        -> 4 blocks/CU (2x the latency-hiding of round 3).
//   Gather: 4 lanes/node iterate the node's CSR bucket (indexed, no chase),
//           each lane covers 16 dims = 32 B of the bf16 feat row.
//   GEMM:  mfma_f32_16x16x32_bf16; wave w owns nodes [w*16,w*16+16),
//          4 j-tiles x 4 K-chunks = 16 MFMA per wave.
// ---------------------------------------------------------------------------
__global__ __launch_bounds__(256) void sage_fused(
    const unsigned short* __restrict__ featb, const int* __restrict__ row_ptr,
    const int* __restrict__ cnt, const int2* __restrict__ csr,
    const float* __restrict__ Ws, const float* __restrict__ bs,
    const float* __restrict__ Wn, const float* __restrict__ bn,
    float* __restrict__ out, int N) {
  __shared__ unsigned short An[64][LPAD];
  __shared__ unsigned short Bw[64][LPAD];

  const int t = threadIdx.x;
  const int n0 = blockIdx.x * 64;

  // Stage W (both matrices are [j][k] row-major, j-major in LDS: no transpose)
  for (int i = t; i < 1024; i += 256) {
    int j = i >> 4, c4 = i & 15;
    float4 w4 = reinterpret_cast<const float4*>(Ws)[i];
    float4 n4 = reinterpret_cast<const float4*>(Wn)[i];
    uint2 ow = make_uint2(pack2(w4.x, w4.y), pack2(w4.z, w4.w));
    uint2 on = make_uint2(pack2(n4.x, n4.y), pack2(n4.z, n4.w));
    *reinterpret_cast<uint2*>(&Bw[j][c4 * 4]) = ow;
    *reinterpret_cast<uint2*>(&Bw[j][64 + c4 * 4]) = on;
  }

  // Stage self-feat rows (bf16, coalesced 16B loads, contiguous LDS writes)
  for (int i = t; i < 512; i += 256) {
    int nl = i >> 3, h = i & 7;
    int gn = n0 + nl;
    uint4 v = make_uint4(0u, 0u, 0u, 0u);
    if (gn < N) v = reinterpret_cast<const uint4*>(featb)[(size_t)gn * 8 + h];
    *reinterpret_cast<uint4*>(&An[nl][h * 8]) = v;
  }

  // Gather: 4 lanes per node; lane q covers dims [q*16, q*16+16)
  {
    int nl = t >> 2, q = t & 3;
    int gn = n0 + nl;
    float acc[16];
#pragma unroll
    for (int i = 0; i < 16; ++i) acc[i] = 0.f;
    if (gn < N) {
      int beg = row_ptr[gn];
      int deg = cnt[gn];
      const uint4* fb = reinterpret_cast<const uint4*>(featb);
      for (int j = 0; j < deg; ++j) {
        int2 e = csr[beg + j];  // broadcast across the 4 lanes
        float w = __int_as_float(e.y);
        const uint4* fr = fb + (size_t)e.x * 8 + q * 2;
        uint4 u0 = fr[0], u1 = fr[1];
        acc[0]  += w * bf16lo(u0.x); acc[1]  += w * bf16hi(u0.x);
        acc[2]  += w * bf16lo(u0.y); acc[3]  += w * bf16hi(u0.y);
        acc[4]  += w * bf16lo(u0.z); acc[5]  += w * bf16hi(u0.z);
        acc[6]  += w * bf16lo(u0.w); acc[7]  += w * bf16hi(u0.w);
        acc[8]  += w * bf16lo(u1.x); acc[9]  += w * bf16hi(u1.x);
        acc[10] += w * bf16lo(u1.y); acc[11] += w * bf16hi(u1.y);
        acc[12] += w * bf16lo(u1.z); acc[13] += w * bf16hi(u1.z);
        acc[14] += w * bf16lo(u1.w); acc[15] += w * bf16hi(u1.w);
      }
      float inv = 1.0f / fmaxf((float)deg, 1.0f);
#pragma unroll
      for (int i = 0; i < 16; ++i) acc[i] *= inv;
    }
    uint4 o0, o1;
    o0.x = pack2(acc[0], acc[1]);   o0.y = pack2(acc[2], acc[3]);
    o0.z = pack2(acc[4], acc[5]);   o0.w = pack2(acc[6], acc[7]);
    o1.x = pack2(acc[8], acc[9]);   o1.y = pack2(acc[10], acc[11]);
    o1.z = pack2(acc[12], acc[13]); o1.w = pack2(acc[14], acc[15]);
    *reinterpret_cast<uint4*>(&An[nl][64 + q * 16]) = o0;
    *reinterpret_cast<uint4*>(&An[nl][64 + q * 16 + 8]) = o1;
  }
  __syncthreads();

  // MFMA phase
  const int wv = t >> 6;
  const int ln = t & 63;
  const int col = ln & 15;   // A row m / B col n / D col
  const int quad = ln >> 4;  // k-subchunk selector / D row group

  floatx4 acc[4];
#pragma unroll
  for (int jt = 0; jt < 4; ++jt) {
    float b = bs[jt * 16 + col] + bn[jt * 16 + col];
    acc[jt] = (floatx4){b, b, b, b};
  }

#pragma unroll
  for (int kk = 0; kk < 4; ++kk) {
    bf16x8 af = *reinterpret_cast<const bf16x8*>(&An[wv * 16 + col][kk * 32 + quad * 8]);
#pragma unroll
    for (int jt = 0; jt < 4; ++jt) {
      bf16x8 bf = *reinterpret_cast<const bf16x8*>(&Bw[jt * 16 + col][kk * 32 + quad * 8]);
      acc[jt] = __builtin_amdgcn_mfma_f32_16x16x32_bf16(af, bf, acc[jt], 0, 0, 0);
    }
  }

#pragma unroll
  for (int jt = 0; jt < 4; ++jt) {
#pragma unroll
    for (int r = 0; r < 4; ++r) {
      int m = quad * 4 + r;
      int gn = n0 + wv * 16 + m;
      if (gn < N) out[(size_t)gn * 64 + jt * 16 + col] = acc[jt][r];
    }
  }
}

extern "C" void kernel_launch(void* const* d_in, const int* in_sizes, int n_in,
                              void* d_out, int out_size, void* d_ws, size_t ws_size,
                              hipStream_t stream) {
  const float* feat = (const float*)d_in[0];
  const int*   src  = (const int*)d_in[1];
  const int*   dst  = (const int*)d_in[2];
  const float* ew   = (const float*)d_in[3];
  const float* em   = (const float*)d_in[4];
  const float* Ws   = (const float*)d_in[5];
  const float* bs   = (const float*)d_in[6];
  const float* Wn   = (const float*)d_in[7];
  const float* bn   = (const float*)d_in[8];
  float* out = (float*)d_out;

  const int N = in_sizes[0] / 64;  // 100000
  const int E = in_sizes[1];       // 1200000

  // Workspace: featb [N*64 bf16] 12.8MB | csr [E int2] 9.6MB | cnt,row_ptr,
  // cursor [N int each] | partials [256 int]  -> ~23.6 MB total
  unsigned short* featb = (unsigned short*)d_ws;
  int2* csr      = (int2*)(featb + (size_t)N * 64);
  int*  cnt      = (int*)(csr + E);
  int*  row_ptr  = cnt + N;
  int*  cursor   = row_ptr + N;
  int*  partials = cursor + N;

  hipMemsetAsync(cnt, 0, (size_t)N * sizeof(int), stream);

  int nChunks = N * 8;  // 8-float conversion chunks
  int prepThreads = (E > nChunks) ? E : nChunks;
  int gP = (prepThreads + 255) / 256;
  int gE = (E + 255) / 256;
  int gN = (N + 255) / 256;
  int nScan = (N + SCAN_TILE - 1) / SCAN_TILE;  // 49

  k_prep<<<gP, 256, 0, stream>>>(feat, dst, cnt, featb, E, nChunks);
  k_scan1<<<nScan, SCAN_TPB, 0, stream>>>(cnt, row_ptr, partials, N);
  k_scan2<<<1, 256, 0, stream>>>(partials, nScan);
  k_scan3<<<gN, 256, 0, stream>>>(row_ptr, partials, cursor, N);
  k_fill<<<gE, 256, 0, stream>>>(src, dst, ew, em, cursor, csr, E);

  int gF = (N + 63) / 64;
  sage_fused<<<gF, 256, 0, stream>>>(featb, row_ptr, cnt, csr,
                                     Ws, bs, Wn, bn, out, N);
}